// Round 1
// baseline (120.763 us; speedup 1.0000x reference)
//
#include <hip/hip_runtime.h>

#define NMAX 64

// Kernel 1: find each molecule's start offset from sorted batch_indices,
// and zero the scalar accumulator out[0] (harness poisons d_out to 0xAA).
__global__ void offsets_kernel(const int* __restrict__ batch_indices, int N,
                               int* __restrict__ offsets, float* __restrict__ out) {
    int i = blockIdx.x * blockDim.x + threadIdx.x;
    if (i == 0) out[0] = 0.0f;
    if (i < N) {
        int b = batch_indices[i];
        if (i == 0 || batch_indices[i - 1] != b) offsets[b] = i;
    }
}

// Kernel 2: one wave (64 lanes) per molecule. Lane t = atom t.
__global__ __launch_bounds__(64) void mol_kernel(
    const float* __restrict__ coords,      // [N,3] flat
    const int*   __restrict__ species,     // [N]
    const int*   __restrict__ num_atoms,   // [B]
    const float* __restrict__ radii,       // [95]
    const int*   __restrict__ offsets,     // [B] (ws)
    float* __restrict__ out,               // [1 + 3N]
    int Bm) {
    const int b = blockIdx.x;
    const int t = threadIdx.x;
    const int n = num_atoms[b];
    if (n <= 0) return;
    const int off = offsets[b];

    __shared__ float sc[3 * NMAX];  // xyz interleaved, same layout as memory
    __shared__ float sr[NMAX];

    // Coalesced cooperative load of 3n coords.
    const size_t base = 3 * (size_t)off;
    for (int k = t; k < 3 * n; k += 64) sc[k] = coords[base + k];
    if (t < n) sr[t] = radii[species[off + t]];
    __syncthreads();

    float x = 0.f, y = 0.f, z = 0.f, r = 0.f;
    if (t < n) {
        x = sc[3 * t + 0];
        y = sc[3 * t + 1];
        z = sc[3 * t + 2];
        r = sr[t];
    }

    // Wave-reduce coordinate sums for the segment mean (block == one wave of 64).
    float sx = x, sy = y, sz = z;
    #pragma unroll
    for (int d = 32; d > 0; d >>= 1) {
        sx += __shfl_down(sx, d);
        sy += __shfl_down(sy, d);
        sz += __shfl_down(sz, d);
    }
    const float invn = 1.0f / (float)n;
    const float mx = __shfl(sx, 0) * invn;
    const float my = __shfl(sy, 0) * invn;
    const float mz = __shfl(sz, 0) * invn;

    // Pairwise repulsion penalty: full matrix, diagonal excluded (matches ref).
    float pen = 0.0f;
    if (t < n) {
        for (int j = 0; j < n; ++j) {
            float dx = x - sc[3 * j + 0];
            float dy = y - sc[3 * j + 1];
            float dz = z - sc[3 * j + 2];
            float d2 = dx * dx + dy * dy + dz * dz + 1e-8f;
            float dist = sqrtf(d2);
            float thr = (r + sr[j]) * 0.8f;
            float v = thr - dist;
            pen += (j != t && v > 0.0f) ? v * v : 0.0f;
        }
    }
    #pragma unroll
    for (int d = 32; d > 0; d >>= 1) pen += __shfl_down(pen, d);
    if (t == 0 && n > 1) {
        atomicAdd(out, pen * invn / (float)Bm);
    }

    // Coalesced centered write: out[1 + 3*off + k] = sc[k] - mean[k % 3]
    for (int k = t; k < 3 * n; k += 64) {
        int c = k - 3 * (k / 3);
        float m = (c == 0) ? mx : (c == 1) ? my : mz;
        out[1 + base + k] = sc[k] - m;
    }
}

extern "C" void kernel_launch(void* const* d_in, const int* in_sizes, int n_in,
                              void* d_out, int out_size, void* d_ws, size_t ws_size,
                              hipStream_t stream) {
    const float* cart_coords   = (const float*)d_in[0];
    const int*   species       = (const int*)d_in[1];
    const int*   batch_indices = (const int*)d_in[2];
    const int*   num_atoms     = (const int*)d_in[3];
    const float* radii_table   = (const float*)d_in[4];

    const int N  = in_sizes[0] / 3;   // cart_coords is [N,3]
    const int Bm = in_sizes[3];       // num_atoms is [B]

    int* offsets = (int*)d_ws;        // B ints of scratch
    float* out = (float*)d_out;

    offsets_kernel<<<(N + 255) / 256, 256, 0, stream>>>(batch_indices, N, offsets, out);
    mol_kernel<<<Bm, 64, 0, stream>>>(cart_coords, species, num_atoms, radii_table,
                                      offsets, out, Bm);
}

// Round 2
// 86.488 us; speedup vs baseline: 1.3963x; 1.3963x over previous
//
#include <hip/hip_runtime.h>

#define NMAX 64
#define MPB 4   // molecules (waves) per block

// Kernel 1: molecule start offsets from sorted batch_indices.
__global__ void offsets_kernel(const int* __restrict__ batch_indices, int N,
                               int* __restrict__ offsets) {
    int i = blockIdx.x * blockDim.x + threadIdx.x;
    if (i < N) {
        int b = batch_indices[i];
        if (i == 0 || batch_indices[i - 1] != b) offsets[b] = i;
    }
}

// Kernel 2: one wave per molecule, MPB waves per block.
__global__ __launch_bounds__(64 * MPB) void mol_kernel(
    const float* __restrict__ coords,      // [N,3] flat
    const int*   __restrict__ species,     // [N]
    const int*   __restrict__ num_atoms,   // [B]
    const float* __restrict__ radii,       // [95]
    const int*   __restrict__ offsets,     // [B] (ws)
    float* __restrict__ penv,              // [B] per-molecule penalty (ws)
    float* __restrict__ out,               // [1 + 3N]
    int Bm) {
    const int w  = threadIdx.x >> 6;          // wave id in block
    const int tw = threadIdx.x & 63;          // lane id
    const int m  = blockIdx.x * MPB + w;      // molecule id

    __shared__ float4 s4[MPB][NMAX];          // {x, y, z, r} per atom

    int n = 0, off = 0;
    size_t base = 0;
    if (m < Bm) {
        n = num_atoms[m];
        off = offsets[m];
        base = 3 * (size_t)off;
        // Coalesced cooperative load of 3n coords, scattered into float4 slots.
        for (int k = tw; k < 3 * n; k += 64) {
            int atom = k / 3;
            int c = k - 3 * atom;
            ((float*)&s4[w][atom])[c] = coords[base + k];
        }
        if (tw < n) s4[w][tw].w = radii[species[off + tw]];
    }
    __syncthreads();
    if (m >= Bm || n <= 0) {
        if (m < Bm && tw == 0) penv[m] = 0.0f;
        return;
    }

    float x = 0.f, y = 0.f, z = 0.f, r = 0.f;
    if (tw < n) {
        float4 a = s4[w][tw];
        x = a.x; y = a.y; z = a.z; r = a.w;
    }

    // Wave-reduce coordinate sums for the segment mean.
    float sx = x, sy = y, sz = z;
    #pragma unroll
    for (int d = 32; d > 0; d >>= 1) {
        sx += __shfl_down(sx, d);
        sy += __shfl_down(sy, d);
        sz += __shfl_down(sz, d);
    }
    const float invn = 1.0f / (float)n;
    const float mx = __shfl(sx, 0) * invn;
    const float my = __shfl(sy, 0) * invn;
    const float mz = __shfl(sz, 0) * invn;

    // Pairwise repulsion: one broadcast ds_read_b128 per j.
    float pen = 0.0f;
    if (tw < n) {
        for (int j = 0; j < n; ++j) {
            float4 aj = s4[w][j];
            float dx = x - aj.x;
            float dy = y - aj.y;
            float dz = z - aj.z;
            float d2 = dx * dx + dy * dy + dz * dz + 1e-8f;
            float dist = sqrtf(d2);
            float thr = (r + aj.w) * 0.8f;
            float v = thr - dist;
            pen += (j != tw && v > 0.0f) ? v * v : 0.0f;
        }
    }
    #pragma unroll
    for (int d = 32; d > 0; d >>= 1) pen += __shfl_down(pen, d);
    if (tw == 0) penv[m] = (n > 1) ? pen * invn : 0.0f;

    // Coalesced centered write.
    for (int k = tw; k < 3 * n; k += 64) {
        int atom = k / 3;
        int c = k - 3 * atom;
        float v = ((float*)&s4[w][atom])[c];
        float mval = (c == 0) ? mx : (c == 1) ? my : mz;
        out[1 + base + k] = v - mval;
    }
}

// Kernel 3: sum 4104 per-molecule penalties -> out[0].
__global__ void reduce_kernel(const float* __restrict__ penv, int Bm,
                              float* __restrict__ out) {
    __shared__ float sdata[4];
    int t = threadIdx.x;
    float s = 0.f;
    for (int i = t; i < Bm; i += 256) s += penv[i];
    #pragma unroll
    for (int d = 32; d > 0; d >>= 1) s += __shfl_down(s, d);
    if ((t & 63) == 0) sdata[t >> 6] = s;
    __syncthreads();
    if (t == 0) out[0] = (sdata[0] + sdata[1] + sdata[2] + sdata[3]) / (float)Bm;
}

extern "C" void kernel_launch(void* const* d_in, const int* in_sizes, int n_in,
                              void* d_out, int out_size, void* d_ws, size_t ws_size,
                              hipStream_t stream) {
    const float* cart_coords   = (const float*)d_in[0];
    const int*   species       = (const int*)d_in[1];
    const int*   batch_indices = (const int*)d_in[2];
    const int*   num_atoms     = (const int*)d_in[3];
    const float* radii_table   = (const float*)d_in[4];

    const int N  = in_sizes[0] / 3;   // cart_coords is [N,3]
    const int Bm = in_sizes[3];       // num_atoms is [B]

    int*   offsets = (int*)d_ws;                 // B ints
    float* penv    = (float*)d_ws + Bm;          // B floats
    float* out     = (float*)d_out;

    offsets_kernel<<<(N + 255) / 256, 256, 0, stream>>>(batch_indices, N, offsets);
    mol_kernel<<<(Bm + MPB - 1) / MPB, 64 * MPB, 0, stream>>>(
        cart_coords, species, num_atoms, radii_table, offsets, penv, out, Bm);
    reduce_kernel<<<1, 256, 0, stream>>>(penv, Bm, out);
}

// Round 3
// 81.573 us; speedup vs baseline: 1.4804x; 1.0603x over previous
//
#include <hip/hip_runtime.h>

#define NMAX 64
#define MPB 4   // molecules (waves) per block

// Kernel 1: molecule start offsets from sorted batch_indices (boundary detect).
__global__ void offsets_kernel(const int* __restrict__ batch_indices, int N,
                               int* __restrict__ offsets) {
    int i = blockIdx.x * blockDim.x + threadIdx.x;
    if (i < N) {
        int b = batch_indices[i];
        if (i == 0 || batch_indices[i - 1] != b) offsets[b] = i;
    }
}

// Kernel 2: one wave per molecule, MPB waves per block. Lane t = atom t.
__global__ __launch_bounds__(64 * MPB) void mol_kernel(
    const float* __restrict__ coords,      // [N,3] flat
    const int*   __restrict__ species,     // [N]
    const int*   __restrict__ num_atoms,   // [B]
    const float* __restrict__ radii,       // [95]
    const int*   __restrict__ offsets,     // [B] (ws)
    float* __restrict__ penv,              // [B] per-molecule penalty (ws)
    float* __restrict__ out,               // [1 + 3N]
    int Bm) {
    const int w  = threadIdx.x >> 6;          // wave id in block
    const int tw = threadIdx.x & 63;          // lane id
    const int m  = blockIdx.x * MPB + w;      // molecule id

    __shared__ float4 s4[MPB][NMAX];          // {x, y, z, r} per atom (wave-private slice)

    int n = 0, off = 0;
    if (m < Bm) {
        n = num_atoms[m];
        off = offsets[m];
    }

    // Per-lane direct load: lane t owns atom t. 64 lanes cover a contiguous
    // 768 B region -> cache-line coalesced; no div/mod staging loop.
    float x = 0.f, y = 0.f, z = 0.f, r = 0.f;
    if (tw < n) {
        const float* cp = coords + 3 * (size_t)(off + tw);
        x = cp[0]; y = cp[1]; z = cp[2];
        r = radii[species[off + tw]];
    }
    s4[w][tw] = make_float4(x, y, z, r);
    __syncthreads();
    if (m >= Bm || n <= 0) return;

    // Wave-reduce coordinate sums for the segment mean (inactive lanes hold 0).
    float sx = x, sy = y, sz = z;
    #pragma unroll
    for (int d = 32; d > 0; d >>= 1) {
        sx += __shfl_down(sx, d);
        sy += __shfl_down(sy, d);
        sz += __shfl_down(sz, d);
    }
    const float invn = 1.0f / (float)n;
    const float mx = __shfl(sx, 0) * invn;
    const float my = __shfl(sy, 0) * invn;
    const float mz = __shfl(sz, 0) * invn;

    // Pairwise repulsion: one broadcast ds_read_b128 per j.
    float pen = 0.0f;
    if (tw < n) {
        #pragma unroll 4
        for (int j = 0; j < n; ++j) {
            float4 aj = s4[w][j];
            float dx = x - aj.x;
            float dy = y - aj.y;
            float dz = z - aj.z;
            float d2 = dx * dx + dy * dy + dz * dz + 1e-8f;
            float dist = sqrtf(d2);
            float thr = (r + aj.w) * 0.8f;
            float v = thr - dist;
            pen += (j != tw && v > 0.0f) ? v * v : 0.0f;
        }
    }
    #pragma unroll
    for (int d = 32; d > 0; d >>= 1) pen += __shfl_down(pen, d);
    if (tw == 0) penv[m] = (n > 1) ? pen * invn : 0.0f;

    // Centered write straight from registers (contiguous 768 B/wave region).
    if (tw < n) {
        float* op = out + 1 + 3 * (size_t)(off + tw);
        op[0] = x - mx;
        op[1] = y - my;
        op[2] = z - mz;
    }
}

// Kernel 3: sum per-molecule penalties -> out[0] = sum / B.
__global__ void reduce_kernel(const float4* __restrict__ pv4, int n4,
                              const float* __restrict__ tail, int rem,
                              float* __restrict__ out, float invB) {
    __shared__ float sdata[4];
    int t = threadIdx.x;
    float s = 0.f;
    for (int i = t; i < n4; i += 256) {
        float4 v = pv4[i];
        s += v.x + v.y + v.z + v.w;
    }
    if (t < rem) s += tail[t];
    #pragma unroll
    for (int d = 32; d > 0; d >>= 1) s += __shfl_down(s, d);
    if ((t & 63) == 0) sdata[t >> 6] = s;
    __syncthreads();
    if (t == 0) out[0] = (sdata[0] + sdata[1] + sdata[2] + sdata[3]) * invB;
}

extern "C" void kernel_launch(void* const* d_in, const int* in_sizes, int n_in,
                              void* d_out, int out_size, void* d_ws, size_t ws_size,
                              hipStream_t stream) {
    const float* cart_coords   = (const float*)d_in[0];
    const int*   species       = (const int*)d_in[1];
    const int*   batch_indices = (const int*)d_in[2];
    const int*   num_atoms     = (const int*)d_in[3];
    const float* radii_table   = (const float*)d_in[4];

    const int N  = in_sizes[0] / 3;   // cart_coords is [N,3]
    const int Bm = in_sizes[3];       // num_atoms is [B]

    int*   offsets = (int*)d_ws;                 // B ints (16B-aligned base)
    float* penv    = (float*)d_ws + Bm;          // B floats (Bm*4 bytes offset)
    float* out     = (float*)d_out;

    offsets_kernel<<<(N + 255) / 256, 256, 0, stream>>>(batch_indices, N, offsets);
    mol_kernel<<<(Bm + MPB - 1) / MPB, 64 * MPB, 0, stream>>>(
        cart_coords, species, num_atoms, radii_table, offsets, penv, out, Bm);

    const int n4  = Bm / 4;
    const int rem = Bm - 4 * n4;
    reduce_kernel<<<1, 256, 0, stream>>>((const float4*)penv, n4,
                                         penv + 4 * n4, rem, out, 1.0f / (float)Bm);
}